// Round 7
// baseline (548.123 us; speedup 1.0000x reference)
//
#include <hip/hip_runtime.h>

typedef unsigned short ushort_t;
typedef unsigned short ushort8 __attribute__((ext_vector_type(8)));
typedef __bf16 bf16x8 __attribute__((ext_vector_type(8)));
typedef float f32x4 __attribute__((ext_vector_type(4)));
typedef float f32x16 __attribute__((ext_vector_type(16)));
typedef unsigned uint32x4 __attribute__((ext_vector_type(4)));

#define DEV __device__ __forceinline__

// ---------- helpers ----------
DEV ushort_t f2bf(float f) {
  unsigned u = __builtin_bit_cast(unsigned, f);
  u += 0x7FFFu + ((u >> 16) & 1u);   // RNE (no NaNs in this workload)
  return (ushort_t)(u >> 16);
}
DEV float bf2f(ushort_t u) {
  return __builtin_bit_cast(float, ((unsigned)u) << 16);
}
DEV void gload_lds16(const void* g, void* s) {
  __builtin_amdgcn_global_load_lds(
      (__attribute__((address_space(1))) void*)(size_t)g,
      (__attribute__((address_space(3))) void*)(size_t)s, 16, 0, 0);
}
DEV f32x16 mfma32(ushort8 a, ushort8 b, f32x16 c) {
  return __builtin_amdgcn_mfma_f32_32x32x16_bf16(
      __builtin_bit_cast(bf16x8, a), __builtin_bit_cast(bf16x8, b), c, 0, 0, 0);
}
DEV f32x16 zero16() {
  f32x16 z;
#pragma unroll
  for (int i = 0; i < 16; ++i) z[i] = 0.f;
  return z;
}
DEV unsigned cvtpk(float lo, float hi2) {  // u32 = {bf16(hi2), bf16(lo)}
  unsigned r;
  asm("v_cvt_pk_bf16_f32 %0, %1, %2" : "=v"(r) : "v"(lo), "v"(hi2));
  return r;
}
// x'[l] = l<32 ? x[l] : y[l-32];  y'[l] = l<32 ? x[l+32] : y[l]
DEV void swap32(unsigned &x, unsigned &y) {
#if __has_builtin(__builtin_amdgcn_permlane32_swap)
  auto t = __builtin_amdgcn_permlane32_swap(x, y, false, false);
  x = (unsigned)t[0];
  y = (unsigned)t[1];
#else
  unsigned xs = (unsigned)__shfl_xor((int)x, 32, 64);
  unsigned ys = (unsigned)__shfl_xor((int)y, 32, 64);
  bool h = (threadIdx.x & 63) >= 32;
  unsigned nx = h ? ys : x;
  unsigned ny = h ? y : xs;
  x = nx; y = ny;
#endif
}
DEV void barx() {  // raw barrier, no vmcnt drain; compiler memory fence
  asm volatile("" ::: "memory");
  __builtin_amdgcn_s_barrier();
  asm volatile("" ::: "memory");
}
#define GATE_VM0 asm volatile("s_waitcnt vmcnt(0)" ::: "memory")
#define GATE_VM8 asm volatile("s_waitcnt vmcnt(8)" ::: "memory")

// ---------- 1) f32 -> bf16 cast ----------
__global__ void cast_bf16(const float4* __restrict__ in,
                          ushort4* __restrict__ out, int n4) {
  int stride = gridDim.x * blockDim.x;
  for (int i = blockIdx.x * blockDim.x + threadIdx.x; i < n4; i += stride) {
    float4 v = in[i];
    out[i] = make_ushort4(f2bf(v.x), f2bf(v.y), f2bf(v.z), f2bf(v.w));
  }
}

// ---------- 2) GEMM 256x192, mfma32, 1-barrier dbuf pipeline ----------
// 8 waves 4M x 2N, per-wave 64x96 (2x3 tiles of 32x32), BK=64, LDS 112 KiB.
// Ledger (1 barrier + 1 vmcnt(0) per tile):
//   iter t: issue stage(t+1 -> buf db^1) [WAR-safe: buf db^1's readers were
//   iter t-1, all done before the barrier ending t-1]; compute tile t from
//   buf db (~1900 cy >> 900 cy HBM latency, so the trailing vmcnt(0) drain
//   of the 7 staging loads is fully latency-hidden); vmcnt(0); s_barrier.
// Chunk swizzle phys = log ^ (row&7) both-sides; 32-row frag reads are
// 2 lanes/slot in each 16-lane LDS cycle -> conflict-free.
template <int OUT_BF16, int ADD_BIAS>
__global__ __launch_bounds__(512, 2)
void gemmT(const ushort_t* __restrict__ A, const ushort_t* __restrict__ Bw,
           const float* __restrict__ bias, void* __restrict__ Cp,
           int M, int N, int K) {
  __shared__ ushort_t As[2][256 * 64];
  __shared__ ushort_t Bs[2][192 * 64];
  const int tid = threadIdx.x;
  const int w = tid >> 6, l = tid & 63;
  const int c = l & 31, hi = l >> 5;
  const int wm = w >> 1, wn = w & 1;
  // XCD-chunked bijective swizzle (nwg % 8 == 0 for both grids)
  const int gx = gridDim.x;
  const int nwg = gx * gridDim.y;
  const int id = blockIdx.y * gx + blockIdx.x;
  const int swz = (id & 7) * (nwg >> 3) + (id >> 3);
  const int m0 = (swz / gx) * 256, n0 = (swz % gx) * 192;
  const int NT = K >> 6;

  // staging: instr covers 64 rows; lane u -> row u>>3, chunk u&7;
  // source k-offset pre-swizzled: chunk ^ (row&7)
  int srow[4], soff[4];
#pragma unroll
  for (int i = 0; i < 4; ++i) {
    int u = i * 512 + tid;
    int row = u >> 3;
    srow[i] = row;
    soff[i] = ((u & 7) ^ (row & 7)) * 8;
  }

  auto stA = [&](int i, int t, int b) {
    gload_lds16(A + (size_t)(m0 + srow[i]) * K + t * 64 + soff[i],
                As[b] + (i * 512 + w * 64) * 8);
  };
  auto stB = [&](int i, int t, int b) {
    gload_lds16(Bw + (size_t)(n0 + srow[i]) * K + t * 64 + soff[i],
                Bs[b] + (i * 512 + w * 64) * 8);
  };
  // mfma32 A-frag: lane holds rows wm*64+mi*32+c, k = ks*16 + hi*8 + j
  auto rdA = [&](int b, int mi, int ks) -> ushort8 {
    int row = wm * 64 + mi * 32 + c;   // row&7 == c&7
    return *(const ushort8*)(As[b] + row * 64 + ((2 * ks + hi) ^ (c & 7)) * 8);
  };
  auto rdB = [&](int b, int ni, int ks) -> ushort8 {
    int row = wn * 96 + ni * 32 + c;   // row&7 == c&7
    return *(const ushort8*)(Bs[b] + row * 64 + ((2 * ks + hi) ^ (c & 7)) * 8);
  };

  f32x16 acc[2][3];
#pragma unroll
  for (int i = 0; i < 2; ++i)
#pragma unroll
    for (int j = 0; j < 3; ++j) acc[i][j] = zero16();

  // prologue: stage t0 -> buf0, drain, barrier
  stA(0, 0, 0); stA(1, 0, 0); stA(2, 0, 0); stA(3, 0, 0);
  stB(0, 0, 0); stB(1, 0, 0); stB(2, 0, 0);
  GATE_VM0;
  barx();

  for (int t = 0; t < NT; ++t) {
    const int db = t & 1;
    const bool pre = (t + 1 < NT);
    if (pre) {   // issue next-tile staging first (latency hides under compute)
      stA(0, t + 1, db ^ 1); stA(1, t + 1, db ^ 1);
      stA(2, t + 1, db ^ 1); stA(3, t + 1, db ^ 1);
      stB(0, t + 1, db ^ 1); stB(1, t + 1, db ^ 1); stB(2, t + 1, db ^ 1);
    }
    asm volatile("" ::: "memory");
    __builtin_amdgcn_s_setprio(1);
#pragma unroll
    for (int ks = 0; ks < 4; ++ks) {
      ushort8 a0 = rdA(db, 0, ks), a1 = rdA(db, 1, ks);
      ushort8 b0 = rdB(db, 0, ks), b1 = rdB(db, 1, ks), b2 = rdB(db, 2, ks);
      acc[0][0] = mfma32(a0, b0, acc[0][0]);
      acc[0][1] = mfma32(a0, b1, acc[0][1]);
      acc[0][2] = mfma32(a0, b2, acc[0][2]);
      acc[1][0] = mfma32(a1, b0, acc[1][0]);
      acc[1][1] = mfma32(a1, b1, acc[1][1]);
      acc[1][2] = mfma32(a1, b2, acc[1][2]);
    }
    __builtin_amdgcn_s_setprio(0);
    if (pre) GATE_VM0;   // t+1 landed; issued ~1900cy ago -> hidden
    barx();              // all waves done reading buf db; buf db now free
  }

  // epilogue: D col = c (N-dim), row = (reg&3)+8*(reg>>2)+4*hi (M-dim)
#pragma unroll
  for (int mi = 0; mi < 2; ++mi) {
#pragma unroll
    for (int ni = 0; ni < 3; ++ni) {
#pragma unroll
      for (int reg = 0; reg < 16; ++reg) {
        int row = m0 + wm * 64 + mi * 32 + (reg & 3) + 8 * (reg >> 2) + 4 * hi;
        int col = n0 + wn * 96 + ni * 32 + c;
        float v = acc[mi][ni][reg];
        if (ADD_BIAS) v += bias[col];
        if (OUT_BF16)
          ((ushort_t*)Cp)[(size_t)row * N + col] = f2bf(v);
        else
          ((float*)Cp)[(size_t)row * N + col] = v;
      }
    }
  }
}

// ---------- 3) RMSNorm + RoPE (Q,K row-major) + V transpose to [B,H,D,L] ----
__global__ __launch_bounds__(256)
void norm_rope(const ushort_t* __restrict__ qkv, const float* __restrict__ pe,
               const float* __restrict__ qs, const float* __restrict__ ksc,
               ushort_t* __restrict__ qb, ushort_t* __restrict__ kb,
               ushort_t* __restrict__ vtg) {
  __shared__ ushort_t Vt_lds[128 * 64];   // [d][token], XOR-swizzled
  const int tid = threadIdx.x;
  const int w = tid >> 6, lane = tid & 63;
  const int tb = blockIdx.x, h = blockIdx.y;
  const int bl0 = tb * 64;
  const int b = bl0 >> 11, l0 = bl0 & 2047;
  const int i2 = lane * 2;

  const float sq0 = qs[i2], sq1 = qs[i2 + 1];
  const float sk0 = ksc[i2], sk1 = ksc[i2 + 1];
  const float QSC = 0.12751744f;  // log2(e) / sqrt(128): softmax in base-2

  for (int t = 0; t < 16; ++t) {
    const int bl = bl0 + w * 16 + t;
    const float4 p4 = *(const float4*)(pe + (size_t)bl * 256 + lane * 4);
    const size_t src = (size_t)bl * 9216 + h * 128 + i2;
    const size_t dst = ((size_t)(b * 24 + h) * 2048 + (bl & 2047)) * 128 + i2;
    {  // Q
      unsigned u = *(const unsigned*)(qkv + src);
      float x0 = bf2f((ushort_t)(u & 0xFFFFu)), x1 = bf2f((ushort_t)(u >> 16));
      float ss = x0 * x0 + x1 * x1;
#pragma unroll
      for (int mm = 32; mm; mm >>= 1) ss += __shfl_xor(ss, mm, 64);
      float rr = rsqrtf(ss * (1.f / 128.f) + 1e-6f);
      float y0 = x0 * rr * sq0, y1 = x1 * rr * sq1;
      float o0 = (p4.x * y0 + p4.y * y1) * QSC;
      float o1 = (p4.z * y0 + p4.w * y1) * QSC;
      *(unsigned*)(qb + dst) = (unsigned)f2bf(o0) | ((unsigned)f2bf(o1) << 16);
    }
    {  // K
      unsigned u = *(const unsigned*)(qkv + src + 3072);
      float x0 = bf2f((ushort_t)(u & 0xFFFFu)), x1 = bf2f((ushort_t)(u >> 16));
      float ss = x0 * x0 + x1 * x1;
#pragma unroll
      for (int mm = 32; mm; mm >>= 1) ss += __shfl_xor(ss, mm, 64);
      float rr = rsqrtf(ss * (1.f / 128.f) + 1e-6f);
      float y0 = x0 * rr * sk0, y1 = x1 * rr * sk1;
      float o0 = p4.x * y0 + p4.y * y1;
      float o1 = p4.z * y0 + p4.w * y1;
      *(unsigned*)(kb + dst) = (unsigned)f2bf(o0) | ((unsigned)f2bf(o1) << 16);
    }
  }

  {  // V -> LDS transposed
    const ushort_t* vsrc = qkv + (size_t)(bl0 + lane) * 9216 + 6144 + h * 128;
#pragma unroll
    for (int i = 0; i < 4; ++i) {
      int oct = w * 4 + i;
      ushort8 vv = *(const ushort8*)(vsrc + oct * 8);
#pragma unroll
      for (int j = 0; j < 8; ++j) {
        int d = oct * 8 + j;
        int ba = (d * 128 + lane * 2) ^ (j << 4);
        *(ushort_t*)((char*)Vt_lds + ba) = vv[j];
      }
    }
  }
  __syncthreads();

  {  // coalesced V^T rows to global [B,H,D,L]
    const int d = tid >> 1, half = tid & 1;
    ushort_t* orow = vtg + ((size_t)(b * 24 + h) * 128 + d) * 2048 + l0 + half * 32;
#pragma unroll
    for (int q = 0; q < 4; ++q) {
      int lb = d * 128 + half * 64 + q * 16;
      ushort8 vv = *(const ushort8*)((char*)Vt_lds + (lb ^ ((d & 7) << 4)));
      *(ushort8*)(orow + q * 8) = vv;
    }
  }
}

// ---------- 4) flash attention: swapped 32x32, double-buffered K/V ----------
__global__ __launch_bounds__(256, 2)
void attn_fwd(const ushort_t* __restrict__ qb, const ushort_t* __restrict__ kb,
              const ushort_t* __restrict__ vt, ushort_t* __restrict__ ob) {
  __shared__ ushort_t Ks[2][64 * 128];    // [key][d], phys chunk = log ^ (key&15)
  __shared__ ushort_t Vts[2][128 * 64];   // [d][key], phys chunk = log ^ (d&7)
  const int tid = threadIdx.x;
  const int w = tid >> 6, l = tid & 63;
  const int c = l & 31, hi = l >> 5;
  // XCD-chunked swizzle (768 blocks, 16 q-tiles x 48 bh)
  const int id = blockIdx.y * 16 + blockIdx.x;
  const int swz = (id & 7) * 96 + (id >> 3);
  const int bh = swz >> 4;
  const int q0 = (swz & 15) * 128 + w * 32;

  const ushort_t* qrow = qb + ((size_t)bh * 2048 + q0 + c) * 128;
  ushort8 qf[8];
#pragma unroll
  for (int s = 0; s < 8; ++s)
    qf[s] = *(const ushort8*)(qrow + s * 16 + hi * 8);

  f32x16 o[4];
#pragma unroll
  for (int dt = 0; dt < 4; ++dt) o[dt] = zero16();
  float m = -1e30f, lp = 0.f;   // m wave-uniform; lp row-c partial sum

  const ushort_t* kbase = kb + (size_t)bh * 2048 * 128;
  const ushort_t* vbase = vt + (size_t)bh * 128 * 2048;

  auto stage = [&](int t, int b) {
#pragma unroll
    for (int i = 0; i < 4; ++i) {
      int u = w * 256 + i * 64 + l;
      int kr = u >> 4, kc = (u & 15) ^ (kr & 15);
      gload_lds16(kbase + (size_t)(t * 64 + kr) * 128 + kc * 8,
                  Ks[b] + (w * 256 + i * 64) * 8);
      int vr = u >> 3, vc = (u & 7) ^ (vr & 7);
      gload_lds16(vbase + (size_t)vr * 2048 + t * 64 + vc * 8,
                  Vts[b] + (w * 256 + i * 64) * 8);
    }
  };

  stage(0, 0);   // prologue

  for (int t = 0; t < 32; ++t) {
    const int db = t & 1;
    if (t < 31) {
      stage(t + 1, db ^ 1);
      GATE_VM8;          // drains tile t's 8; t+1's stay in flight
    } else {
      GATE_VM0;
    }
    barx();

    // S^T = K . Q^T : two 32-key tiles, 8 d-steps of k=16
    f32x16 s0 = zero16(), s1 = zero16();
    __builtin_amdgcn_s_setprio(1);
#pragma unroll
    for (int ds = 0; ds < 8; ++ds) {
      int ch = (2 * ds + hi) ^ (c & 15);
      ushort8 k0 = *(const ushort8*)(Ks[db] + c * 128 + ch * 8);
      ushort8 k1 = *(const ushort8*)(Ks[db] + (32 + c) * 128 + ch * 8);
      s0 = mfma32(k0, qf[ds], s0);
      s1 = mfma32(k1, qf[ds], s1);
    }
    __builtin_amdgcn_s_setprio(0);

    // online softmax (base-2), wave-uniform max, defer THR=8
    float p[32];
#pragma unroll
    for (int rr = 0; rr < 16; ++rr) { p[rr] = s0[rr]; p[16 + rr] = s1[rr]; }
    float pmax = p[0];
#pragma unroll
    for (int rr = 1; rr < 32; ++rr) pmax = fmaxf(pmax, p[rr]);
    if (!__all(pmax <= m + 8.f)) {
      float wm = pmax;
#pragma unroll
      for (int d = 1; d < 64; d <<= 1) wm = fmaxf(wm, __shfl_xor(wm, d, 64));
      float mn = fmaxf(m, wm);        // wave-uniform new max
      float fs = exp2f(m - mn);       // layout-independent rescale
      m = mn;
      lp *= fs;
#pragma unroll
      for (int dt = 0; dt < 4; ++dt)
#pragma unroll
        for (int e = 0; e < 16; ++e) o[dt][e] *= fs;
    }
    float rs = 0.f;
#pragma unroll
    for (int rr = 0; rr < 32; ++rr) { p[rr] = exp2f(p[rr] - m); rs += p[rr]; }
    lp += rs;

    // P -> A-frag words: 4 cvt_pk + 2 permlane32_swap per 16-key step (T12)
    uint32x4 pk[4];
#pragma unroll
    for (int ks = 0; ks < 4; ++ks) {
      unsigned a0 = cvtpk(p[ks * 8 + 0], p[ks * 8 + 1]);
      unsigned a1 = cvtpk(p[ks * 8 + 2], p[ks * 8 + 3]);
      unsigned a2 = cvtpk(p[ks * 8 + 4], p[ks * 8 + 5]);
      unsigned a3 = cvtpk(p[ks * 8 + 6], p[ks * 8 + 7]);
      swap32(a0, a2);
      swap32(a1, a3);
      pk[ks] = uint32x4{a0, a1, a2, a3};
    }

    // O += P . V
    __builtin_amdgcn_s_setprio(1);
#pragma unroll
    for (int dt = 0; dt < 4; ++dt) {
#pragma unroll
      for (int ks = 0; ks < 4; ++ks) {
        int ch = (2 * ks + hi) ^ (c & 7);
        ushort8 vf = *(const ushort8*)(Vts[db] + (32 * dt + c) * 64 + ch * 8);
        o[dt] = mfma32(__builtin_bit_cast(ushort8, pk[ks]), vf, o[dt]);
      }
    }
    __builtin_amdgcn_s_setprio(0);
    barx();   // WAR guard: next iter stages into buf db
  }

  // epilogue: lr lives at lane q (row c); O rows are crow(r,hi) -> shfl
  float lr = lp + __shfl_xor(lp, 32, 64);
  float rl = 1.f / lr;
  const int b = bh / 24, h = bh % 24;
  ushort_t* obase = ob + ((size_t)b * 2048 + q0) * 3072 + h * 128 + c;
#pragma unroll
  for (int rr = 0; rr < 16; ++rr) {
    int q = (rr & 3) + 8 * (rr >> 2) + 4 * hi;
    float os = __shfl(rl, q, 64);   // denominator of row q
#pragma unroll
    for (int dt = 0; dt < 4; ++dt)
      obase[(size_t)q * 3072 + dt * 32] = f2bf(o[dt][rr] * os);
  }
}

// ---------- launch ----------
extern "C" void kernel_launch(void* const* d_in, const int* in_sizes, int n_in,
                              void* d_out, int out_size, void* d_ws, size_t ws_size,
                              hipStream_t stream) {
  const float* x    = (const float*)d_in[0];
  const float* pe   = (const float*)d_in[1];
  const float* qkvw = (const float*)d_in[2];
  const float* pw   = (const float*)d_in[3];
  const float* pb   = (const float*)d_in[4];
  const float* qsc  = (const float*)d_in[5];
  const float* ksc  = (const float*)d_in[6];
  float* out = (float*)d_out;

  char* p = (char*)d_ws;
  ushort_t* x_bf  = (ushort_t*)(p + 0);          // 25,165,824
  ushort_t* o_bf  = x_bf;                        // reuse: x dead after GEMM1
  ushort_t* qw_bf = (ushort_t*)(p + 25165824);   // 56,623,104
  ushort_t* pw_bf = (ushort_t*)(p + 81788928);   // 18,874,368
  ushort_t* qkv   = (ushort_t*)(p + 100663296);  // 75,497,472
  ushort_t* qh    = (ushort_t*)(p + 176160768);  // 25,165,824
  ushort_t* kh    = (ushort_t*)(p + 201326592);  // 25,165,824
  ushort_t* vtg   = (ushort_t*)(p + 226492416);  // 25,165,824 (V^T [B,H,D,L])

  cast_bf16<<<2048, 256, 0, stream>>>((const float4*)x,    (ushort4*)x_bf,  4096 * 3072 / 4);
  cast_bf16<<<2048, 256, 0, stream>>>((const float4*)qkvw, (ushort4*)qw_bf, 9216 * 3072 / 4);
  cast_bf16<<<2048, 256, 0, stream>>>((const float4*)pw,   (ushort4*)pw_bf, 3072 * 3072 / 4);

  gemmT<1, 0><<<dim3(48, 16), 512, 0, stream>>>(x_bf, qw_bf, nullptr, qkv, 4096, 9216, 3072);
  norm_rope<<<dim3(64, 24), 256, 0, stream>>>(qkv, pe, qsc, ksc, qh, kh, vtg);
  attn_fwd<<<dim3(16, 48), 256, 0, stream>>>(qh, kh, vtg, o_bf);
  gemmT<0, 1><<<dim3(16, 16), 512, 0, stream>>>(o_bf, pw_bf, pb, out, 4096, 3072, 3072);
}

// Round 8
// 514.705 us; speedup vs baseline: 1.0649x; 1.0649x over previous
//
#include <hip/hip_runtime.h>

typedef unsigned short ushort_t;
typedef unsigned short ushort8 __attribute__((ext_vector_type(8)));
typedef __bf16 bf16x8 __attribute__((ext_vector_type(8)));
typedef float f32x4 __attribute__((ext_vector_type(4)));
typedef float f32x16 __attribute__((ext_vector_type(16)));
typedef unsigned uint32x4 __attribute__((ext_vector_type(4)));

#define DEV __device__ __forceinline__

// ---------- helpers ----------
DEV ushort_t f2bf(float f) {
  unsigned u = __builtin_bit_cast(unsigned, f);
  u += 0x7FFFu + ((u >> 16) & 1u);   // RNE (no NaNs in this workload)
  return (ushort_t)(u >> 16);
}
DEV float bf2f(ushort_t u) {
  return __builtin_bit_cast(float, ((unsigned)u) << 16);
}
DEV void gload_lds16(const void* g, void* s) {
  __builtin_amdgcn_global_load_lds(
      (__attribute__((address_space(1))) void*)(size_t)g,
      (__attribute__((address_space(3))) void*)(size_t)s, 16, 0, 0);
}
DEV f32x4 mfma16(ushort8 a, ushort8 b, f32x4 c) {
  return __builtin_amdgcn_mfma_f32_16x16x32_bf16(
      __builtin_bit_cast(bf16x8, a), __builtin_bit_cast(bf16x8, b), c, 0, 0, 0);
}
DEV f32x16 mfma32(ushort8 a, ushort8 b, f32x16 c) {
  return __builtin_amdgcn_mfma_f32_32x32x16_bf16(
      __builtin_bit_cast(bf16x8, a), __builtin_bit_cast(bf16x8, b), c, 0, 0, 0);
}
DEV f32x16 zero16() {
  f32x16 z;
#pragma unroll
  for (int i = 0; i < 16; ++i) z[i] = 0.f;
  return z;
}
DEV unsigned cvtpk(float lo, float hi2) {  // u32 = {bf16(hi2), bf16(lo)}
  unsigned r;
  asm("v_cvt_pk_bf16_f32 %0, %1, %2" : "=v"(r) : "v"(lo), "v"(hi2));
  return r;
}
// x'[l] = l<32 ? x[l] : y[l-32];  y'[l] = l<32 ? x[l+32] : y[l]
DEV void swap32(unsigned &x, unsigned &y) {
#if __has_builtin(__builtin_amdgcn_permlane32_swap)
  auto t = __builtin_amdgcn_permlane32_swap(x, y, false, false);
  x = (unsigned)t[0];
  y = (unsigned)t[1];
#else
  unsigned xs = (unsigned)__shfl_xor((int)x, 32, 64);
  unsigned ys = (unsigned)__shfl_xor((int)y, 32, 64);
  bool h = (threadIdx.x & 63) >= 32;
  unsigned nx = h ? ys : x;
  unsigned ny = h ? y : xs;
  x = nx; y = ny;
#endif
}
DEV void barx() {  // raw barrier, no vmcnt drain; compiler memory fence
  asm volatile("" ::: "memory");
  __builtin_amdgcn_s_barrier();
  asm volatile("" ::: "memory");
}
#define GATE_VM0 asm volatile("s_waitcnt vmcnt(0)" ::: "memory")
#define GATE_VM8 asm volatile("s_waitcnt vmcnt(8)" ::: "memory")

// ---------- 1) f32 -> bf16 cast ----------
__global__ void cast_bf16(const float4* __restrict__ in,
                          ushort4* __restrict__ out, int n4) {
  int stride = gridDim.x * blockDim.x;
  for (int i = blockIdx.x * blockDim.x + threadIdx.x; i < n4; i += stride) {
    float4 v = in[i];
    out[i] = make_ushort4(f2bf(v.x), f2bf(v.y), f2bf(v.z), f2bf(v.w));
  }
}

// ---------- 2) GEMM 256xBN, 16x16 frags, 1-barrier dbuf: C = A * Bw^T ------
// BN=288 for GEMM1 (grid 32x16=512 = exactly 2/CU), BN=192 for GEMM2
// (grid 16x16=256 = 1/CU). 8 waves 4M x 2N; per-wave 64 x BN/2 (4 mi x NIW ni
// of 16x16). Rationale (r6/r7/m201): per-tile wall time ~const (~4000cy)
// across schedules -> amortize with more MFMAs/tile (576 @BN=288 vs 384).
// Ledger: iter t stages t+1 -> buf db^1 (WAR-safe: db^1 readers finished
// before barrier ending t-1); compute tile t (~2800cy >> HBM latency);
// vmcnt(0) (count-agnostic: B-tail staging is wave-predicated); s_barrier.
// LDS chunk swizzle phys = log ^ (row&7), both sides (r6: measured 0 confl).
template <int NIW, int OUT_BF16, int ADD_BIAS>
__global__ __launch_bounds__(512, 2)
void gemmT(const ushort_t* __restrict__ A, const ushort_t* __restrict__ Bw,
           const float* __restrict__ bias, void* __restrict__ Cp,
           int M, int N, int K) {
  constexpr int BN = NIW * 32;            // 288 or 192
  constexpr int BCH_FULL = (BN * 8) / 512;      // full B staging instrs
  constexpr int BCH_TAIL = (BN * 8) % 512;      // leftover chunks (0 or 256)
  __shared__ ushort_t As[2][256 * 64];
  __shared__ ushort_t Bs[2][BN * 64];
  const int tid = threadIdx.x;
  const int w = tid >> 6, l = tid & 63;
  const int g = l >> 4, r = l & 15;
  const int wm = w >> 1, wn = w & 1;
  // XCD-chunked bijective swizzle (nwg % 8 == 0 for both grids)
  const int gx = gridDim.x;
  const int nwg = gx * gridDim.y;
  const int id = blockIdx.y * gx + blockIdx.x;
  const int swz = (id & 7) * (nwg >> 3) + (id >> 3);
  const int m0 = (swz / gx) * 256, n0 = (swz % gx) * BN;
  const int NT = K >> 6;

  // staging: instr i covers chunks [i*512, i*512+512); lane u -> row u>>3,
  // slot u&7; source k-chunk pre-swizzled (u&7)^(row&7)
  auto stA = [&](int i, int t, int b) {
    int u = i * 512 + tid;
    int row = u >> 3;
    gload_lds16(A + (size_t)(m0 + row) * K + t * 64 + (((u & 7) ^ (row & 7)) * 8),
                As[b] + (i * 512 + w * 64) * 8);
  };
  auto stB = [&](int i, int t, int b) {
    int u = i * 512 + tid;
    int row = u >> 3;
    gload_lds16(Bw + (size_t)(n0 + row) * K + t * 64 + (((u & 7) ^ (row & 7)) * 8),
                Bs[b] + (i * 512 + w * 64) * 8);
  };
  auto stage = [&](int t, int b) {
#pragma unroll
    for (int i = 0; i < 4; ++i) stA(i, t, b);
#pragma unroll
    for (int i = 0; i < BCH_FULL; ++i) stB(i, t, b);
    if (BCH_TAIL && w < (BCH_TAIL >> 6)) stB(BCH_FULL, t, b);
  };
  // 16x16 frag reads (r6 pattern, measured 0 conflicts)
  auto rdA = [&](int b, int mi, int kk) -> ushort8 {
    int row = wm * 64 + mi * 16 + r;   // row&7 == r&7
    return *(const ushort8*)(As[b] + row * 64 + ((((kk << 2) + g) ^ (r & 7)) * 8));
  };
  auto rdB = [&](int b, int ni, int kk) -> ushort8 {
    int row = wn * (NIW * 16) + ni * 16 + r;   // NIW*16 % 8 == 0 -> row&7==r&7
    return *(const ushort8*)(Bs[b] + row * 64 + ((((kk << 2) + g) ^ (r & 7)) * 8));
  };

  f32x4 acc[4][NIW];
#pragma unroll
  for (int i = 0; i < 4; ++i)
#pragma unroll
    for (int j = 0; j < NIW; ++j) acc[i][j] = f32x4{0.f, 0.f, 0.f, 0.f};

  // prologue
  stage(0, 0);
  GATE_VM0;
  barx();

  for (int t = 0; t < NT; ++t) {
    const int db = t & 1;
    const bool pre = (t + 1 < NT);
    if (pre) stage(t + 1, db ^ 1);   // latency hides under compute
    asm volatile("" ::: "memory");
    __builtin_amdgcn_s_setprio(1);
#pragma unroll
    for (int kk = 0; kk < 2; ++kk) {
      ushort8 a0 = rdA(db, 0, kk), a1 = rdA(db, 1, kk);
      ushort8 a2 = rdA(db, 2, kk), a3 = rdA(db, 3, kk);
#pragma unroll
      for (int ni = 0; ni < NIW; ++ni) {
        ushort8 b = rdB(db, ni, kk);
        acc[0][ni] = mfma16(a0, b, acc[0][ni]);
        acc[1][ni] = mfma16(a1, b, acc[1][ni]);
        acc[2][ni] = mfma16(a2, b, acc[2][ni]);
        acc[3][ni] = mfma16(a3, b, acc[3][ni]);
      }
    }
    __builtin_amdgcn_s_setprio(0);
    if (pre) GATE_VM0;   // t+1 landed; issued ~2800cy ago -> hidden
    barx();              // buf db free for t+2's staging
  }

  // epilogue: D row = 4g+j (M-dim), col = r (N-dim)
#pragma unroll
  for (int mi = 0; mi < 4; ++mi) {
#pragma unroll
    for (int ni = 0; ni < NIW; ++ni) {
#pragma unroll
      for (int j = 0; j < 4; ++j) {
        int row = m0 + wm * 64 + mi * 16 + g * 4 + j;
        int col = n0 + wn * (NIW * 16) + ni * 16 + r;
        float v = acc[mi][ni][j];
        if (ADD_BIAS) v += bias[col];
        if (OUT_BF16)
          ((ushort_t*)Cp)[(size_t)row * N + col] = f2bf(v);
        else
          ((float*)Cp)[(size_t)row * N + col] = v;
      }
    }
  }
}

// ---------- 3) RMSNorm + RoPE (Q,K row-major) + V transpose to [B,H,D,L] ----
__global__ __launch_bounds__(256)
void norm_rope(const ushort_t* __restrict__ qkv, const float* __restrict__ pe,
               const float* __restrict__ qs, const float* __restrict__ ksc,
               ushort_t* __restrict__ qb, ushort_t* __restrict__ kb,
               ushort_t* __restrict__ vtg) {
  __shared__ ushort_t Vt_lds[128 * 64];   // [d][token], XOR-swizzled
  const int tid = threadIdx.x;
  const int w = tid >> 6, lane = tid & 63;
  const int tb = blockIdx.x, h = blockIdx.y;
  const int bl0 = tb * 64;
  const int b = bl0 >> 11, l0 = bl0 & 2047;
  const int i2 = lane * 2;

  const float sq0 = qs[i2], sq1 = qs[i2 + 1];
  const float sk0 = ksc[i2], sk1 = ksc[i2 + 1];
  const float QSC = 0.12751744f;  // log2(e) / sqrt(128): softmax in base-2

  for (int t = 0; t < 16; ++t) {
    const int bl = bl0 + w * 16 + t;
    const float4 p4 = *(const float4*)(pe + (size_t)bl * 256 + lane * 4);
    const size_t src = (size_t)bl * 9216 + h * 128 + i2;
    const size_t dst = ((size_t)(b * 24 + h) * 2048 + (bl & 2047)) * 128 + i2;
    {  // Q
      unsigned u = *(const unsigned*)(qkv + src);
      float x0 = bf2f((ushort_t)(u & 0xFFFFu)), x1 = bf2f((ushort_t)(u >> 16));
      float ss = x0 * x0 + x1 * x1;
#pragma unroll
      for (int mm = 32; mm; mm >>= 1) ss += __shfl_xor(ss, mm, 64);
      float rr = rsqrtf(ss * (1.f / 128.f) + 1e-6f);
      float y0 = x0 * rr * sq0, y1 = x1 * rr * sq1;
      float o0 = (p4.x * y0 + p4.y * y1) * QSC;
      float o1 = (p4.z * y0 + p4.w * y1) * QSC;
      *(unsigned*)(qb + dst) = (unsigned)f2bf(o0) | ((unsigned)f2bf(o1) << 16);
    }
    {  // K
      unsigned u = *(const unsigned*)(qkv + src + 3072);
      float x0 = bf2f((ushort_t)(u & 0xFFFFu)), x1 = bf2f((ushort_t)(u >> 16));
      float ss = x0 * x0 + x1 * x1;
#pragma unroll
      for (int mm = 32; mm; mm >>= 1) ss += __shfl_xor(ss, mm, 64);
      float rr = rsqrtf(ss * (1.f / 128.f) + 1e-6f);
      float y0 = x0 * rr * sk0, y1 = x1 * rr * sk1;
      float o0 = p4.x * y0 + p4.y * y1;
      float o1 = p4.z * y0 + p4.w * y1;
      *(unsigned*)(kb + dst) = (unsigned)f2bf(o0) | ((unsigned)f2bf(o1) << 16);
    }
  }

  {  // V -> LDS transposed
    const ushort_t* vsrc = qkv + (size_t)(bl0 + lane) * 9216 + 6144 + h * 128;
#pragma unroll
    for (int i = 0; i < 4; ++i) {
      int oct = w * 4 + i;
      ushort8 vv = *(const ushort8*)(vsrc + oct * 8);
#pragma unroll
      for (int j = 0; j < 8; ++j) {
        int d = oct * 8 + j;
        int ba = (d * 128 + lane * 2) ^ (j << 4);
        *(ushort_t*)((char*)Vt_lds + ba) = vv[j];
      }
    }
  }
  __syncthreads();

  {  // coalesced V^T rows to global [B,H,D,L]
    const int d = tid >> 1, half = tid & 1;
    ushort_t* orow = vtg + ((size_t)(b * 24 + h) * 128 + d) * 2048 + l0 + half * 32;
#pragma unroll
    for (int q = 0; q < 4; ++q) {
      int lb = d * 128 + half * 64 + q * 16;
      ushort8 vv = *(const ushort8*)((char*)Vt_lds + (lb ^ ((d & 7) << 4)));
      *(ushort8*)(orow + q * 8) = vv;
    }
  }
}

// ---------- 4) flash attention: swapped 32x32, double-buffered K/V ----------
__global__ __launch_bounds__(256, 2)
void attn_fwd(const ushort_t* __restrict__ qb, const ushort_t* __restrict__ kb,
              const ushort_t* __restrict__ vt, ushort_t* __restrict__ ob) {
  __shared__ ushort_t Ks[2][64 * 128];    // [key][d], phys chunk = log ^ (key&15)
  __shared__ ushort_t Vts[2][128 * 64];   // [d][key], phys chunk = log ^ (d&7)
  const int tid = threadIdx.x;
  const int w = tid >> 6, l = tid & 63;
  const int c = l & 31, hi = l >> 5;
  // XCD-chunked swizzle (768 blocks, 16 q-tiles x 48 bh)
  const int id = blockIdx.y * 16 + blockIdx.x;
  const int swz = (id & 7) * 96 + (id >> 3);
  const int bh = swz >> 4;
  const int q0 = (swz & 15) * 128 + w * 32;

  const ushort_t* qrow = qb + ((size_t)bh * 2048 + q0 + c) * 128;
  ushort8 qf[8];
#pragma unroll
  for (int s = 0; s < 8; ++s)
    qf[s] = *(const ushort8*)(qrow + s * 16 + hi * 8);

  f32x16 o[4];
#pragma unroll
  for (int dt = 0; dt < 4; ++dt) o[dt] = zero16();
  float m = -1e30f, lp = 0.f;   // m wave-uniform; lp row-c partial sum

  const ushort_t* kbase = kb + (size_t)bh * 2048 * 128;
  const ushort_t* vbase = vt + (size_t)bh * 128 * 2048;

  auto stage = [&](int t, int b) {
#pragma unroll
    for (int i = 0; i < 4; ++i) {
      int u = w * 256 + i * 64 + l;
      int kr = u >> 4, kc = (u & 15) ^ (kr & 15);
      gload_lds16(kbase + (size_t)(t * 64 + kr) * 128 + kc * 8,
                  Ks[b] + (w * 256 + i * 64) * 8);
      int vr = u >> 3, vc = (u & 7) ^ (vr & 7);
      gload_lds16(vbase + (size_t)vr * 2048 + t * 64 + vc * 8,
                  Vts[b] + (w * 256 + i * 64) * 8);
    }
  };

  stage(0, 0);   // prologue

  for (int t = 0; t < 32; ++t) {
    const int db = t & 1;
    if (t < 31) {
      stage(t + 1, db ^ 1);
      GATE_VM8;          // drains tile t's 8; t+1's stay in flight
    } else {
      GATE_VM0;
    }
    barx();

    // S^T = K . Q^T : two 32-key tiles, 8 d-steps of k=16
    f32x16 s0 = zero16(), s1 = zero16();
    __builtin_amdgcn_s_setprio(1);
#pragma unroll
    for (int ds = 0; ds < 8; ++ds) {
      int ch = (2 * ds + hi) ^ (c & 15);
      ushort8 k0 = *(const ushort8*)(Ks[db] + c * 128 + ch * 8);
      ushort8 k1 = *(const ushort8*)(Ks[db] + (32 + c) * 128 + ch * 8);
      s0 = mfma32(k0, qf[ds], s0);
      s1 = mfma32(k1, qf[ds], s1);
    }
    __builtin_amdgcn_s_setprio(0);

    // online softmax (base-2), wave-uniform max, defer THR=8
    float p[32];
#pragma unroll
    for (int rr = 0; rr < 16; ++rr) { p[rr] = s0[rr]; p[16 + rr] = s1[rr]; }
    float pmax = p[0];
#pragma unroll
    for (int rr = 1; rr < 32; ++rr) pmax = fmaxf(pmax, p[rr]);
    if (!__all(pmax <= m + 8.f)) {
      float wm = pmax;
#pragma unroll
      for (int d = 1; d < 64; d <<= 1) wm = fmaxf(wm, __shfl_xor(wm, d, 64));
      float mn = fmaxf(m, wm);        // wave-uniform new max
      float fs = exp2f(m - mn);       // layout-independent rescale
      m = mn;
      lp *= fs;
#pragma unroll
      for (int dt = 0; dt < 4; ++dt)
#pragma unroll
        for (int e = 0; e < 16; ++e) o[dt][e] *= fs;
    }
    float rs = 0.f;
#pragma unroll
    for (int rr = 0; rr < 32; ++rr) { p[rr] = exp2f(p[rr] - m); rs += p[rr]; }
    lp += rs;

    // P -> A-frag words: 4 cvt_pk + 2 permlane32_swap per 16-key step (T12)
    uint32x4 pk[4];
#pragma unroll
    for (int ks = 0; ks < 4; ++ks) {
      unsigned a0 = cvtpk(p[ks * 8 + 0], p[ks * 8 + 1]);
      unsigned a1 = cvtpk(p[ks * 8 + 2], p[ks * 8 + 3]);
      unsigned a2 = cvtpk(p[ks * 8 + 4], p[ks * 8 + 5]);
      unsigned a3 = cvtpk(p[ks * 8 + 6], p[ks * 8 + 7]);
      swap32(a0, a2);
      swap32(a1, a3);
      pk[ks] = uint32x4{a0, a1, a2, a3};
    }

    // O += P . V
    __builtin_amdgcn_s_setprio(1);
#pragma unroll
    for (int dt = 0; dt < 4; ++dt) {
#pragma unroll
      for (int ks = 0; ks < 4; ++ks) {
        int ch = (2 * ks + hi) ^ (c & 7);
        ushort8 vf = *(const ushort8*)(Vts[db] + (32 * dt + c) * 64 + ch * 8);
        o[dt] = mfma32(__builtin_bit_cast(ushort8, pk[ks]), vf, o[dt]);
      }
    }
    __builtin_amdgcn_s_setprio(0);
    barx();   // WAR guard: next iter stages into buf db
  }

  // epilogue: lr lives at lane q (row c); O rows are crow(r,hi) -> shfl
  float lr = lp + __shfl_xor(lp, 32, 64);
  float rl = 1.f / lr;
  const int b = bh / 24, h = bh % 24;
  ushort_t* obase = ob + ((size_t)b * 2048 + q0) * 3072 + h * 128 + c;
#pragma unroll
  for (int rr = 0; rr < 16; ++rr) {
    int q = (rr & 3) + 8 * (rr >> 2) + 4 * hi;
    float os = __shfl(rl, q, 64);   // denominator of row q
#pragma unroll
    for (int dt = 0; dt < 4; ++dt)
      obase[(size_t)q * 3072 + dt * 32] = f2bf(o[dt][rr] * os);
  }
}

// ---------- launch ----------
extern "C" void kernel_launch(void* const* d_in, const int* in_sizes, int n_in,
                              void* d_out, int out_size, void* d_ws, size_t ws_size,
                              hipStream_t stream) {
  const float* x    = (const float*)d_in[0];
  const float* pe   = (const float*)d_in[1];
  const float* qkvw = (const float*)d_in[2];
  const float* pw   = (const float*)d_in[3];
  const float* pb   = (const float*)d_in[4];
  const float* qsc  = (const float*)d_in[5];
  const float* ksc  = (const float*)d_in[6];
  float* out = (float*)d_out;

  char* p = (char*)d_ws;
  ushort_t* x_bf  = (ushort_t*)(p + 0);          // 25,165,824
  ushort_t* o_bf  = x_bf;                        // reuse: x dead after GEMM1
  ushort_t* qw_bf = (ushort_t*)(p + 25165824);   // 56,623,104
  ushort_t* pw_bf = (ushort_t*)(p + 81788928);   // 18,874,368
  ushort_t* qkv   = (ushort_t*)(p + 100663296);  // 75,497,472
  ushort_t* qh    = (ushort_t*)(p + 176160768);  // 25,165,824
  ushort_t* kh    = (ushort_t*)(p + 201326592);  // 25,165,824
  ushort_t* vtg   = (ushort_t*)(p + 226492416);  // 25,165,824 (V^T [B,H,D,L])

  cast_bf16<<<2048, 256, 0, stream>>>((const float4*)x,    (ushort4*)x_bf,  4096 * 3072 / 4);
  cast_bf16<<<2048, 256, 0, stream>>>((const float4*)qkvw, (ushort4*)qw_bf, 9216 * 3072 / 4);
  cast_bf16<<<2048, 256, 0, stream>>>((const float4*)pw,   (ushort4*)pw_bf, 3072 * 3072 / 4);

  // GEMM1: BN=288 -> grid 32x16 = 512 = 2.00 blocks/CU
  gemmT<9, 1, 0><<<dim3(32, 16), 512, 0, stream>>>(x_bf, qw_bf, nullptr, qkv, 4096, 9216, 3072);
  norm_rope<<<dim3(64, 24), 256, 0, stream>>>(qkv, pe, qsc, ksc, qh, kh, vtg);
  attn_fwd<<<dim3(16, 48), 256, 0, stream>>>(qh, kh, vtg, o_bf);
  // GEMM2: BN=192 -> grid 16x16 = 256 = 1.00 blocks/CU
  gemmT<6, 0, 1><<<dim3(16, 16), 512, 0, stream>>>(o_bf, pw_bf, pb, out, 4096, 3072, 3072);
}